// Round 15
// baseline (3204.091 us; speedup 1.0000x reference)
//
#include <hip/hip_runtime.h>
#include <hip/hip_fp16.h>
#include <math.h>
#include <cstddef>

#define N_PTS 131072
#define SDIM  512
#define D1    513

static constexpr int NITER = 100;
static constexpr int BLK   = 512;            // 8 waves / block
static constexpr int GRID  = 512;            // 2 blocks / CU
static constexpr int WPB   = BLK / 64;       // 8 waves per block
static constexpr int NW    = GRID * WPB;     // 4096 waves
static constexpr int NPAIR = N_PTS / 2;      // 65536 row-pairs
static constexpr int PPW   = NPAIR / NW;     // 16 pairs per wave

#if __has_builtin(__builtin_amdgcn_fdot2)
#define HAVE_FDOT2 1
#else
#define HAVE_FDOT2 0
#endif

typedef _Float16 h2v __attribute__((ext_vector_type(2)));

struct Ws {
  double colsum[514];          // [0..511] spatial, [512] t-sum, [513] cc-sum
  double part[514][GRID];      // column-major per-block partials
  float  meanbuf[2][516];      // [0..511] spatial, [512] time (double-buffered)
  float  t_tab[N_PTS];         // precomputed sqrt(1+|x_i|^2)
};
// fp16 data copy lives at 256B-aligned offset after Ws in d_ws.

__device__ __forceinline__ float2 cvt2(unsigned u) {
  union { unsigned u; __half2 h; } c; c.u = u; return __half22float2(c.h);
}
__device__ __forceinline__ unsigned pack2(float a, float b) {
  union { unsigned u; __half2 h; } c; c.h = __floats2half2_rn(a, b); return c.u;
}
__device__ __forceinline__ h2v ash2(unsigned u) {
  union { unsigned u; h2v h; } c; c.u = u; return c.h;
}

// ---- mean update, all-f32 (series cosh/sinh; no f64 libcalls) ----
// columns c=q*64+l; c<512 spatial, c==512 time
template<bool INIT>
__device__ __forceinline__ void compute_mean(const Ws* __restrict__ ws,
                                             const float* __restrict__ mprev,
                                             int l, float out[9])
{
  if constexpr (INIT) {
    float r[9]; float s2 = 0.f;
    #pragma unroll
    for (int q = 0; q < 9; ++q) {
      int c = q * 64 + l;
      r[q] = (c < D1) ? (float)(ws->colsum[c] * (1.0 / (double)N_PTS)) : 0.f;
      s2 += r[q] * r[q];
    }
    #pragma unroll
    for (int m = 1; m < 64; m <<= 1) s2 += __shfl_xor(s2, m);
    float rt = __shfl(r[8], 0);
    float inv = 1.f / sqrtf(fabsf(s2 - 2.f * rt * rt));
    #pragma unroll
    for (int q = 0; q < 9; ++q) out[q] = r[q] * inv;
  } else {
    const float cc = (float)ws->colsum[513];
    float mv[9], yv[9]; float sy = 0.f;
    #pragma unroll
    for (int q = 0; q < 9; ++q) {
      int c = q * 64 + l;
      mv[q] = 0.f; yv[q] = 0.f;
      if (c < D1) {
        float m  = mprev[c];
        float sv = (float)ws->colsum[c];
        float y  = 0.02f * fmaf(-cc, m, sv) * (1.f / (float)N_PTS);  // y = -R*g
        mv[q] = m; yv[q] = y;
        sy = fmaf(y, y, sy);
      }
    }
    #pragma unroll
    for (int m = 1; m < 64; m <<= 1) sy += __shfl_xor(sy, m);
    float yt = __shfl(yv[8], 0);
    float n = sqrtf(fabsf(sy - 2.f * yt * yt));
    n = fmaxf(n, 1e-5f);
    float ch, sn;
    if (n < 0.25f) {                       // wave-uniform branch; n is tiny in practice
      float nn = n * n;
      ch = 1.f + nn * (0.5f      + nn * (1.f/24.f  + nn * (1.f/720.f)));
      sn = 1.f + nn * (1.f/6.f   + nn * (1.f/120.f + nn * (1.f/5040.f)));
    } else {
      float e = expf(n), ei = 1.f / e;
      ch = 0.5f * (e + ei);
      sn = 0.5f * (e - ei) / n;
    }
    float nm[9]; float s2 = 0.f;
    #pragma unroll
    for (int q = 0; q < 9; ++q) {
      nm[q] = fmaf(ch, mv[q], sn * yv[q]);
      s2 = fmaf(nm[q], nm[q], s2);
    }
    #pragma unroll
    for (int m = 1; m < 64; m <<= 1) s2 += __shfl_xor(s2, m);
    float nt = __shfl(nm[8], 0);
    float inv = 1.f / sqrtf(fabsf(s2 - 2.f * nt * nt));
    #pragma unroll
    for (int q = 0; q < 9; ++q) out[q] = nm[q] * inv;
  }
}

// ================= INIT: f32 read -> t_tab + fp16 copy + w=1 partials =================
__global__ __launch_bounds__(BLK, 4)
void init_kernel(const float* __restrict__ data, __half* __restrict__ hdata,
                 Ws* __restrict__ ws)
{
  const int l    = threadIdx.x & 63;
  const int sl   = l & 31;
  const int half = l >> 5;
  const int wid  = threadIdx.x >> 6;
  const int gw   = blockIdx.x * WPB + wid;

  float accf[16] = {};
  double acc_t = 0.0;

  const int p0 = gw * PPW;

  float4 v0, v1, v2, v3, n0, n1, n2, n3;
  {
    const float4* f4 = (const float4*)(data + (size_t)(2 * p0 + half) * SDIM);
    v0 = f4[2*sl]; v1 = f4[2*sl+1]; v2 = f4[64+2*sl]; v3 = f4[64+2*sl+1];
  }

  for (int k = 0; k < PPW; ++k) {
    if (k + 1 < PPW) {
      const float4* f4 = (const float4*)(data + (size_t)(2 * (p0 + k + 1) + half) * SDIM);
      n0 = f4[2*sl]; n1 = f4[2*sl+1]; n2 = f4[64+2*sl]; n3 = f4[64+2*sl+1];
    } else { n0 = v0; n1 = v1; n2 = v2; n3 = v3; }

    const int row = 2 * (p0 + k) + half;

    {
      uint4 ua, ub;
      ua.x = pack2(v0.x, v0.y); ua.y = pack2(v0.z, v0.w);
      ua.z = pack2(v1.x, v1.y); ua.w = pack2(v1.z, v1.w);
      ub.x = pack2(v2.x, v2.y); ub.y = pack2(v2.z, v2.w);
      ub.z = pack2(v3.x, v3.y); ub.w = pack2(v3.z, v3.w);
      uint4* hb = (uint4*)(hdata + (size_t)row * SDIM);
      hb[sl] = ua; hb[32 + sl] = ub;
    }

    float sqa = v0.x * v0.x;
    sqa = fmaf(v0.y, v0.y, sqa); sqa = fmaf(v0.z, v0.z, sqa); sqa = fmaf(v0.w, v0.w, sqa);
    sqa = fmaf(v1.x, v1.x, sqa); sqa = fmaf(v1.y, v1.y, sqa);
    sqa = fmaf(v1.z, v1.z, sqa); sqa = fmaf(v1.w, v1.w, sqa);
    float sqb = v2.x * v2.x;
    sqb = fmaf(v2.y, v2.y, sqb); sqb = fmaf(v2.z, v2.z, sqb); sqb = fmaf(v2.w, v2.w, sqb);
    sqb = fmaf(v3.x, v3.x, sqb); sqb = fmaf(v3.y, v3.y, sqb);
    sqb = fmaf(v3.z, v3.z, sqb); sqb = fmaf(v3.w, v3.w, sqb);
    float sq = sqa + sqb;
    #pragma unroll
    for (int m = 1; m < 32; m <<= 1) sq += __shfl_xor(sq, m);

    float t = sqrtf(1.0f + sq);
    if (sl == 0) { ws->t_tab[row] = t; acc_t += (double)t; }

    accf[0]  += v0.x; accf[1]  += v0.y; accf[2]  += v0.z; accf[3]  += v0.w;
    accf[4]  += v1.x; accf[5]  += v1.y; accf[6]  += v1.z; accf[7]  += v1.w;
    accf[8]  += v2.x; accf[9]  += v2.y; accf[10] += v2.z; accf[11] += v2.w;
    accf[12] += v3.x; accf[13] += v3.y; accf[14] += v3.z; accf[15] += v3.w;

    v0 = n0; v1 = n1; v2 = n2; v3 = n3;
  }

  #pragma unroll
  for (int i = 0; i < 16; ++i) accf[i] += __shfl_xor(accf[i], 32);
  acc_t += __shfl_xor(acc_t, 32);

  __shared__ double s_red[WPB][514];
  if (half == 0) {
    #pragma unroll
    for (int i = 0; i < 8; ++i) {
      s_red[wid][8*sl + i]       = (double)accf[i];
      s_red[wid][256 + 8*sl + i] = (double)accf[8 + i];
    }
  }
  if (l == 0) { s_red[wid][512] = acc_t; s_red[wid][513] = 0.0; }
  __syncthreads();

  for (int c = threadIdx.x; c < 514; c += BLK) {
    double s = 0.0;
    #pragma unroll
    for (int w2 = 0; w2 < WPB; ++w2) s += s_red[w2][c];
    ws->part[c][blockIdx.x] = s;
  }
}

// ===== ITER: fused f32 mean prologue + fp16 stream, fdot2 dots, 3-stage prefetch ======
template<bool FIRST>
__global__ __launch_bounds__(BLK, 4)
void iter_kernel(const __half* __restrict__ hdata, Ws* __restrict__ ws,
                 const float* __restrict__ mprev, float* __restrict__ mnext)
{
  const int l    = threadIdx.x & 63;
  const int sl   = l & 31;
  const int half = l >> 5;
  const int wid  = threadIdx.x >> 6;
  const int gw   = blockIdx.x * WPB + wid;

  const int p0 = gw * PPW;

#define LDH(Ra, Rb, p) do {                                                   \
    const uint4* b_ = (const uint4*)(hdata + (size_t)(2 * (p) + half) * SDIM);\
    Ra = b_[sl]; Rb = b_[32 + sl];                                            \
  } while (0)

  // pre-issue the first two pair-loads; they cover the prologue latency
  uint4 Aa, Ab, Ba, Bb, Pa, Pb, Qa, Qb, Ra, Rb, Sa, Sb, Ta, Tb, Ua, Ub;
  LDH(Aa, Ab, p0 + 0);
  LDH(Ba, Bb, p0 + 1);

  // prologue: wave 0 computes this iteration's mean (f32, no libcalls);
  // block 0 publishes it for the next iteration.
  __shared__ __align__(16) float s_mean[516];
#if HAVE_FDOT2
  __shared__ __align__(16) unsigned s_meanh[256];   // mean packed to half2
#endif
  if (threadIdx.x < 64) {
    float outm[9];
    compute_mean<FIRST>(ws, mprev, threadIdx.x, outm);
    #pragma unroll
    for (int q = 0; q < 9; ++q) {
      int c = q * 64 + threadIdx.x;
      if (c < D1) {
        s_mean[c] = outm[q];
        if (blockIdx.x == 0) mnext[c] = outm[q];
      }
    }
  }
  __syncthreads();
#if HAVE_FDOT2
  if (threadIdx.x < 256) {
    s_meanh[threadIdx.x] = pack2(s_mean[2*threadIdx.x], s_mean[2*threadIdx.x + 1]);
  }
  __syncthreads();
#endif

  const float m0 = s_mean[512];
#if HAVE_FDOT2
  const uint4 mhA = ((const uint4*)s_meanh)[sl];        // cols 8sl..8sl+7 (half2 x4)
  const uint4 mhB = ((const uint4*)s_meanh)[32 + sl];   // cols 256+8sl..+7
#else
  const float4* mp4 = (const float4*)s_mean;
  const float4 mkA0 = mp4[2*sl],      mkA1 = mp4[2*sl + 1];
  const float4 mkB0 = mp4[64 + 2*sl], mkB1 = mp4[64 + 2*sl + 1];
#endif

  float accf[16] = {};
  double acc_t = 0.0, acc_cc = 0.0;
  const float* __restrict__ ttab = ws->t_tab;

  LDH(Pa, Pb, p0 + 2);
  LDH(Qa, Qb, p0 + 3);
  LDH(Ra, Rb, p0 + 4);
  LDH(Sa, Sb, p0 + 5);
  Ta = Aa; Tb = Ab; Ua = Ba; Ub = Bb;

  // t-value 1-step register pipeline
  float tAc = ttab[2 * p0 + half];
  float tBc = ttab[2 * (p0 + 1) + half];

  for (int kk = 0; kk < PPW; kk += 2) {
    if (kk + 6 < PPW) {
      LDH(Ta, Tb, p0 + kk + 6);
      LDH(Ua, Ub, p0 + kk + 7);
    }
    float tAn = 0.f, tBn = 0.f;
    if (kk + 2 < PPW) {
      tAn = ttab[2 * (p0 + kk + 2) + half];
      tBn = ttab[2 * (p0 + kk + 3) + half];
    }
    const float tA = tAc;
    const float tB = tBc;

    float dotA, dotB;
#if HAVE_FDOT2
    {
      float d0 = __builtin_amdgcn_fdot2(ash2(Aa.x), ash2(mhA.x), 0.f, false);
      d0 = __builtin_amdgcn_fdot2(ash2(Aa.y), ash2(mhA.y), d0, false);
      float d1 = __builtin_amdgcn_fdot2(ash2(Aa.z), ash2(mhA.z), 0.f, false);
      d1 = __builtin_amdgcn_fdot2(ash2(Aa.w), ash2(mhA.w), d1, false);
      float d2 = __builtin_amdgcn_fdot2(ash2(Ab.x), ash2(mhB.x), 0.f, false);
      d2 = __builtin_amdgcn_fdot2(ash2(Ab.y), ash2(mhB.y), d2, false);
      float d3 = __builtin_amdgcn_fdot2(ash2(Ab.z), ash2(mhB.z), 0.f, false);
      d3 = __builtin_amdgcn_fdot2(ash2(Ab.w), ash2(mhB.w), d3, false);
      dotA = (d0 + d1) + (d2 + d3);

      float e0 = __builtin_amdgcn_fdot2(ash2(Ba.x), ash2(mhA.x), 0.f, false);
      e0 = __builtin_amdgcn_fdot2(ash2(Ba.y), ash2(mhA.y), e0, false);
      float e1 = __builtin_amdgcn_fdot2(ash2(Ba.z), ash2(mhA.z), 0.f, false);
      e1 = __builtin_amdgcn_fdot2(ash2(Ba.w), ash2(mhA.w), e1, false);
      float e2 = __builtin_amdgcn_fdot2(ash2(Bb.x), ash2(mhB.x), 0.f, false);
      e2 = __builtin_amdgcn_fdot2(ash2(Bb.y), ash2(mhB.y), e2, false);
      float e3 = __builtin_amdgcn_fdot2(ash2(Bb.z), ash2(mhB.z), 0.f, false);
      e3 = __builtin_amdgcn_fdot2(ash2(Bb.w), ash2(mhB.w), e3, false);
      dotB = (e0 + e1) + (e2 + e3);
    }
#else
    {
      float2 f;
      f = cvt2(Aa.x); float dA  = f.x * mkA0.x;        dA  = fmaf(f.y, mkA0.y, dA);
      f = cvt2(Aa.y); dA  = fmaf(f.x, mkA0.z, dA);     dA  = fmaf(f.y, mkA0.w, dA);
      f = cvt2(Aa.z); dA  = fmaf(f.x, mkA1.x, dA);     dA  = fmaf(f.y, mkA1.y, dA);
      f = cvt2(Aa.w); dA  = fmaf(f.x, mkA1.z, dA);     dA  = fmaf(f.y, mkA1.w, dA);
      f = cvt2(Ab.x); float dA2 = f.x * mkB0.x;        dA2 = fmaf(f.y, mkB0.y, dA2);
      f = cvt2(Ab.y); dA2 = fmaf(f.x, mkB0.z, dA2);    dA2 = fmaf(f.y, mkB0.w, dA2);
      f = cvt2(Ab.z); dA2 = fmaf(f.x, mkB1.x, dA2);    dA2 = fmaf(f.y, mkB1.y, dA2);
      f = cvt2(Ab.w); dA2 = fmaf(f.x, mkB1.z, dA2);    dA2 = fmaf(f.y, mkB1.w, dA2);
      dotA = dA + dA2;

      f = cvt2(Ba.x); float dB  = f.x * mkA0.x;        dB  = fmaf(f.y, mkA0.y, dB);
      f = cvt2(Ba.y); dB  = fmaf(f.x, mkA0.z, dB);     dB  = fmaf(f.y, mkA0.w, dB);
      f = cvt2(Ba.z); dB  = fmaf(f.x, mkA1.x, dB);     dB  = fmaf(f.y, mkA1.y, dB);
      f = cvt2(Ba.w); dB  = fmaf(f.x, mkA1.z, dB);     dB  = fmaf(f.y, mkA1.w, dB);
      f = cvt2(Bb.x); float dB2 = f.x * mkB0.x;        dB2 = fmaf(f.y, mkB0.y, dB2);
      f = cvt2(Bb.y); dB2 = fmaf(f.x, mkB0.z, dB2);    dB2 = fmaf(f.y, mkB0.w, dB2);
      f = cvt2(Bb.z); dB2 = fmaf(f.x, mkB1.x, dB2);    dB2 = fmaf(f.y, mkB1.y, dB2);
      f = cvt2(Bb.w); dB2 = fmaf(f.x, mkB1.z, dB2);    dB2 = fmaf(f.y, mkB1.w, dB2);
      dotB = dB + dB2;
    }
#endif

    #pragma unroll
    for (int m = 1; m < 32; m <<= 1) {
      dotA += __shfl_xor(dotA, m);
      dotB += __shfl_xor(dotB, m);
    }

    const float aA = fmaf(m0, tA, -dotA);
    const float aB = fmaf(m0, tB, -dotB);
    const float xA = fmaxf(aA, 1.0f + 1e-5f);
    const float xB = fmaxf(aB, 1.0f + 1e-5f);
    const float sA = sqrtf(fmaf(xA, xA, -1.0f));
    const float sB = sqrtf(fmaf(xB, xB, -1.0f));
    const float ddA = logf(xA + sA);
    const float ddB = logf(xB + sB);
    const float wA = ddA / sA;
    const float wB = ddB / sB;
    if (sl == 0) {
      acc_cc += fma((double)wA, (double)xA, (double)wB * (double)xB);
      acc_t  += fma((double)wA, (double)tA, (double)wB * (double)tB);
    }

    float2 a0, a1;
    a0 = cvt2(Aa.x); a1 = cvt2(Ba.x);
    accf[0]  = fmaf(wA, a0.x, fmaf(wB, a1.x, accf[0]));
    accf[1]  = fmaf(wA, a0.y, fmaf(wB, a1.y, accf[1]));
    a0 = cvt2(Aa.y); a1 = cvt2(Ba.y);
    accf[2]  = fmaf(wA, a0.x, fmaf(wB, a1.x, accf[2]));
    accf[3]  = fmaf(wA, a0.y, fmaf(wB, a1.y, accf[3]));
    a0 = cvt2(Aa.z); a1 = cvt2(Ba.z);
    accf[4]  = fmaf(wA, a0.x, fmaf(wB, a1.x, accf[4]));
    accf[5]  = fmaf(wA, a0.y, fmaf(wB, a1.y, accf[5]));
    a0 = cvt2(Aa.w); a1 = cvt2(Ba.w);
    accf[6]  = fmaf(wA, a0.x, fmaf(wB, a1.x, accf[6]));
    accf[7]  = fmaf(wA, a0.y, fmaf(wB, a1.y, accf[7]));
    a0 = cvt2(Ab.x); a1 = cvt2(Bb.x);
    accf[8]  = fmaf(wA, a0.x, fmaf(wB, a1.x, accf[8]));
    accf[9]  = fmaf(wA, a0.y, fmaf(wB, a1.y, accf[9]));
    a0 = cvt2(Ab.y); a1 = cvt2(Bb.y);
    accf[10] = fmaf(wA, a0.x, fmaf(wB, a1.x, accf[10]));
    accf[11] = fmaf(wA, a0.y, fmaf(wB, a1.y, accf[11]));
    a0 = cvt2(Ab.z); a1 = cvt2(Bb.z);
    accf[12] = fmaf(wA, a0.x, fmaf(wB, a1.x, accf[12]));
    accf[13] = fmaf(wA, a0.y, fmaf(wB, a1.y, accf[13]));
    a0 = cvt2(Ab.w); a1 = cvt2(Bb.w);
    accf[14] = fmaf(wA, a0.x, fmaf(wB, a1.x, accf[14]));
    accf[15] = fmaf(wA, a0.y, fmaf(wB, a1.y, accf[15]));

    // rotate the 3-stage pipeline
    Aa = Pa; Ab = Pb; Ba = Qa; Bb = Qb;
    Pa = Ra; Pb = Rb; Qa = Sa; Qb = Sb;
    Ra = Ta; Rb = Tb; Sa = Ua; Sb = Ub;
    tAc = tAn; tBc = tBn;
  }
#undef LDH

  #pragma unroll
  for (int i = 0; i < 16; ++i) accf[i] += __shfl_xor(accf[i], 32);
  acc_t  += __shfl_xor(acc_t, 32);
  acc_cc += __shfl_xor(acc_cc, 32);

  __shared__ double s_red[WPB][514];
  if (half == 0) {
    #pragma unroll
    for (int i = 0; i < 8; ++i) {
      s_red[wid][8*sl + i]       = (double)accf[i];
      s_red[wid][256 + 8*sl + i] = (double)accf[8 + i];
    }
  }
  if (l == 0) { s_red[wid][512] = acc_t; s_red[wid][513] = acc_cc; }
  __syncthreads();

  for (int c = threadIdx.x; c < 514; c += BLK) {
    double s = 0.0;
    #pragma unroll
    for (int w2 = 0; w2 < WPB; ++w2) s += s_red[w2][c];
    ws->part[c][blockIdx.x] = s;
  }
}

// ---------------- per-column reduce: one wave per column ----------------
__global__ __launch_bounds__(64)
void colreduce_kernel(Ws* __restrict__ ws)
{
  const int c = blockIdx.x;
  const int l = threadIdx.x;
  const double* col = ws->part[c];
  double s = 0.0;
  #pragma unroll
  for (int k = 0; k < GRID / 64; ++k) s += col[l + 64 * k];
  #pragma unroll
  for (int m = 1; m < 64; m <<= 1) s += __shfl_xor(s, m);
  if (l == 0) ws->colsum[c] = s;
}

// ---------------- final mean (one wave), after the last colreduce ----------------
__global__ __launch_bounds__(64)
void final_kernel(Ws* __restrict__ ws, const float* __restrict__ mprev,
                  float* __restrict__ mnext)
{
  float outm[9];
  compute_mean<false>(ws, mprev, threadIdx.x, outm);
  #pragma unroll
  for (int q = 0; q < 9; ++q) {
    int c = q * 64 + threadIdx.x;
    if (c < D1) mnext[c] = outm[q];
  }
}

__global__ void write_out_kernel(const float* __restrict__ mean, float* __restrict__ out)
{
  int i = threadIdx.x;
  if (i < SDIM) out[i] = mean[i];   // spatial components live at [0..511]
}

extern "C" void kernel_launch(void* const* d_in, const int* in_sizes, int n_in,
                              void* d_out, int out_size, void* d_ws, size_t ws_size,
                              hipStream_t stream)
{
  (void)in_sizes; (void)n_in; (void)out_size; (void)ws_size;
  const float* data = (const float*)d_in[0];
  Ws* ws = (Ws*)d_ws;

  const size_t hoff = (sizeof(Ws) + 255) & ~(size_t)255;
  __half* hdata = (__half*)((char*)d_ws + hoff);

  float* M0 = (float*)((char*)d_ws + offsetof(Ws, meanbuf));        // slot 0
  float* M1 = M0 + 516;                                             // slot 1

  init_kernel<<<dim3(GRID), dim3(BLK), 0, stream>>>(data, hdata, ws);
  colreduce_kernel<<<dim3(514), dim3(64), 0, stream>>>(ws);

  // iter #0: prologue computes mean_0 (INIT semantics) -> writes M0
  iter_kernel<true><<<dim3(GRID), dim3(BLK), 0, stream>>>(hdata, ws, M1, M0);
  colreduce_kernel<<<dim3(514), dim3(64), 0, stream>>>(ws);

  // iters #1..99: prologue computes mean_it from (colsum, mean_{it-1})
  for (int it = 1; it < NITER; ++it) {
    const float* mp = (((it + 1) & 1) == 0) ? M0 : M1;
    float*       mn = ((it & 1) == 0) ? M0 : M1;
    iter_kernel<false><<<dim3(GRID), dim3(BLK), 0, stream>>>(hdata, ws, mp, mn);
    colreduce_kernel<<<dim3(514), dim3(64), 0, stream>>>(ws);
  }

  // mean_100 from the last colreduce + mean_99 (it=99 wrote M1)
  final_kernel<<<dim3(1), dim3(64), 0, stream>>>(ws, M1, M0);
  write_out_kernel<<<dim3(1), dim3(512), 0, stream>>>(M0, (float*)d_out);
}

// Round 16
// 3150.030 us; speedup vs baseline: 1.0172x; 1.0172x over previous
//
#include <hip/hip_runtime.h>
#include <hip/hip_fp16.h>
#include <math.h>
#include <cstddef>

#define N_PTS 131072
#define SDIM  512
#define D1    513

static constexpr int NITER = 100;
static constexpr int BLK   = 512;            // 8 waves / block
static constexpr int GRID  = 512;            // 2 blocks / CU
static constexpr int WPB   = BLK / 64;       // 8 waves per block
static constexpr int NW    = GRID * WPB;     // 4096 waves
static constexpr int NPAIR = N_PTS / 2;      // 65536 row-pairs
static constexpr int PPW   = NPAIR / NW;     // 16 pairs per wave

struct Ws {
  double colsum[514];          // [0..511] spatial, [512] t-sum, [513] cc-sum
  double part[514][GRID];      // column-major per-block partials
  float  meanbuf[2][516];      // [0..511] spatial, [512] time (double-buffered)
  float  t_tab[N_PTS];         // precomputed sqrt(1+|x_i|^2)
};
// fp16 data copy lives at 256B-aligned offset after Ws in d_ws.

__device__ __forceinline__ float2 cvt2(unsigned u) {
  union { unsigned u; __half2 h; } c; c.u = u; return __half22float2(c.h);
}
__device__ __forceinline__ unsigned pack2(float a, float b) {
  union { unsigned u; __half2 h; } c; c.h = __floats2half2_rn(a, b); return c.u;
}

// ---- mean update, all-f32 (series cosh/sinh; no f64 libcalls) ----
// columns c=q*64+l; c<512 spatial, c==512 time
template<bool INIT>
__device__ __forceinline__ void compute_mean(const Ws* __restrict__ ws,
                                             const float* __restrict__ mprev,
                                             int l, float out[9])
{
  if constexpr (INIT) {
    float r[9]; float s2 = 0.f;
    #pragma unroll
    for (int q = 0; q < 9; ++q) {
      int c = q * 64 + l;
      r[q] = (c < D1) ? (float)(ws->colsum[c] * (1.0 / (double)N_PTS)) : 0.f;
      s2 += r[q] * r[q];
    }
    #pragma unroll
    for (int m = 1; m < 64; m <<= 1) s2 += __shfl_xor(s2, m);
    float rt = __shfl(r[8], 0);
    float inv = 1.f / sqrtf(fabsf(s2 - 2.f * rt * rt));
    #pragma unroll
    for (int q = 0; q < 9; ++q) out[q] = r[q] * inv;
  } else {
    const float cc = (float)ws->colsum[513];
    float mv[9], yv[9]; float sy = 0.f;
    #pragma unroll
    for (int q = 0; q < 9; ++q) {
      int c = q * 64 + l;
      mv[q] = 0.f; yv[q] = 0.f;
      if (c < D1) {
        float m  = mprev[c];
        float sv = (float)ws->colsum[c];
        float y  = 0.02f * fmaf(-cc, m, sv) * (1.f / (float)N_PTS);  // y = -R*g
        mv[q] = m; yv[q] = y;
        sy = fmaf(y, y, sy);
      }
    }
    #pragma unroll
    for (int m = 1; m < 64; m <<= 1) sy += __shfl_xor(sy, m);
    float yt = __shfl(yv[8], 0);
    float n = sqrtf(fabsf(sy - 2.f * yt * yt));
    n = fmaxf(n, 1e-5f);
    float ch, sn;
    if (n < 0.25f) {                       // wave-uniform branch; n is tiny in practice
      float nn = n * n;
      ch = 1.f + nn * (0.5f      + nn * (1.f/24.f  + nn * (1.f/720.f)));
      sn = 1.f + nn * (1.f/6.f   + nn * (1.f/120.f + nn * (1.f/5040.f)));
    } else {
      float e = expf(n), ei = 1.f / e;
      ch = 0.5f * (e + ei);
      sn = 0.5f * (e - ei) / n;
    }
    float nm[9]; float s2 = 0.f;
    #pragma unroll
    for (int q = 0; q < 9; ++q) {
      nm[q] = fmaf(ch, mv[q], sn * yv[q]);
      s2 = fmaf(nm[q], nm[q], s2);
    }
    #pragma unroll
    for (int m = 1; m < 64; m <<= 1) s2 += __shfl_xor(s2, m);
    float nt = __shfl(nm[8], 0);
    float inv = 1.f / sqrtf(fabsf(s2 - 2.f * nt * nt));
    #pragma unroll
    for (int q = 0; q < 9; ++q) out[q] = nm[q] * inv;
  }
}

// ================= INIT: f32 read -> t_tab + fp16 copy + w=1 partials =================
__global__ __launch_bounds__(BLK, 4)
void init_kernel(const float* __restrict__ data, __half* __restrict__ hdata,
                 Ws* __restrict__ ws)
{
  const int l    = threadIdx.x & 63;
  const int sl   = l & 31;
  const int half = l >> 5;
  const int wid  = threadIdx.x >> 6;
  const int gw   = blockIdx.x * WPB + wid;

  float accf[16] = {};
  double acc_t = 0.0;

  const int p0 = gw * PPW;

  float4 v0, v1, v2, v3, n0, n1, n2, n3;
  {
    const float4* f4 = (const float4*)(data + (size_t)(2 * p0 + half) * SDIM);
    v0 = f4[2*sl]; v1 = f4[2*sl+1]; v2 = f4[64+2*sl]; v3 = f4[64+2*sl+1];
  }

  for (int k = 0; k < PPW; ++k) {
    if (k + 1 < PPW) {
      const float4* f4 = (const float4*)(data + (size_t)(2 * (p0 + k + 1) + half) * SDIM);
      n0 = f4[2*sl]; n1 = f4[2*sl+1]; n2 = f4[64+2*sl]; n3 = f4[64+2*sl+1];
    } else { n0 = v0; n1 = v1; n2 = v2; n3 = v3; }

    const int row = 2 * (p0 + k) + half;

    {
      uint4 ua, ub;
      ua.x = pack2(v0.x, v0.y); ua.y = pack2(v0.z, v0.w);
      ua.z = pack2(v1.x, v1.y); ua.w = pack2(v1.z, v1.w);
      ub.x = pack2(v2.x, v2.y); ub.y = pack2(v2.z, v2.w);
      ub.z = pack2(v3.x, v3.y); ub.w = pack2(v3.z, v3.w);
      uint4* hb = (uint4*)(hdata + (size_t)row * SDIM);
      hb[sl] = ua; hb[32 + sl] = ub;
    }

    float sqa = v0.x * v0.x;
    sqa = fmaf(v0.y, v0.y, sqa); sqa = fmaf(v0.z, v0.z, sqa); sqa = fmaf(v0.w, v0.w, sqa);
    sqa = fmaf(v1.x, v1.x, sqa); sqa = fmaf(v1.y, v1.y, sqa);
    sqa = fmaf(v1.z, v1.z, sqa); sqa = fmaf(v1.w, v1.w, sqa);
    float sqb = v2.x * v2.x;
    sqb = fmaf(v2.y, v2.y, sqb); sqb = fmaf(v2.z, v2.z, sqb); sqb = fmaf(v2.w, v2.w, sqb);
    sqb = fmaf(v3.x, v3.x, sqb); sqb = fmaf(v3.y, v3.y, sqb);
    sqb = fmaf(v3.z, v3.z, sqb); sqb = fmaf(v3.w, v3.w, sqb);
    float sq = sqa + sqb;
    #pragma unroll
    for (int m = 1; m < 32; m <<= 1) sq += __shfl_xor(sq, m);

    float t = sqrtf(1.0f + sq);
    if (sl == 0) { ws->t_tab[row] = t; acc_t += (double)t; }

    accf[0]  += v0.x; accf[1]  += v0.y; accf[2]  += v0.z; accf[3]  += v0.w;
    accf[4]  += v1.x; accf[5]  += v1.y; accf[6]  += v1.z; accf[7]  += v1.w;
    accf[8]  += v2.x; accf[9]  += v2.y; accf[10] += v2.z; accf[11] += v2.w;
    accf[12] += v3.x; accf[13] += v3.y; accf[14] += v3.z; accf[15] += v3.w;

    v0 = n0; v1 = n1; v2 = n2; v3 = n3;
  }

  #pragma unroll
  for (int i = 0; i < 16; ++i) accf[i] += __shfl_xor(accf[i], 32);
  acc_t += __shfl_xor(acc_t, 32);

  __shared__ double s_red[WPB][514];
  if (half == 0) {
    #pragma unroll
    for (int i = 0; i < 8; ++i) {
      s_red[wid][8*sl + i]       = (double)accf[i];
      s_red[wid][256 + 8*sl + i] = (double)accf[8 + i];
    }
  }
  if (l == 0) { s_red[wid][512] = acc_t; s_red[wid][513] = 0.0; }
  __syncthreads();

  for (int c = threadIdx.x; c < 514; c += BLK) {
    double s = 0.0;
    #pragma unroll
    for (int w2 = 0; w2 < WPB; ++w2) s += s_red[w2][c];
    ws->part[c][blockIdx.x] = s;
  }
}

// ===== ITER: fused f32 mean prologue + fp16 stream, 2 pairs/step, t 1-step pipeline ===
template<bool FIRST>
__global__ __launch_bounds__(BLK, 4)
void iter_kernel(const __half* __restrict__ hdata, Ws* __restrict__ ws,
                 const float* __restrict__ mprev, float* __restrict__ mnext)
{
  const int l    = threadIdx.x & 63;
  const int sl   = l & 31;
  const int half = l >> 5;
  const int wid  = threadIdx.x >> 6;
  const int gw   = blockIdx.x * WPB + wid;

  const int p0 = gw * PPW;

#define LDH(Ra, Rb, p) do {                                                   \
    const uint4* b_ = (const uint4*)(hdata + (size_t)(2 * (p) + half) * SDIM);\
    Ra = b_[sl]; Rb = b_[32 + sl];                                            \
  } while (0)

  // pre-issue the first two pair-loads; they cover the prologue latency
  uint4 Aa, Ab, Ba, Bb, Pa, Pb, Qa, Qb, Ra, Rb, Sa, Sb;
  LDH(Aa, Ab, p0 + 0);
  LDH(Ba, Bb, p0 + 1);

  // prologue: wave 0 computes this iteration's mean (f32, no libcalls);
  // block 0 publishes it for the next iteration.
  __shared__ __align__(16) float s_mean[516];
  if (threadIdx.x < 64) {
    float outm[9];
    compute_mean<FIRST>(ws, mprev, threadIdx.x, outm);
    #pragma unroll
    for (int q = 0; q < 9; ++q) {
      int c = q * 64 + threadIdx.x;
      if (c < D1) {
        s_mean[c] = outm[q];
        if (blockIdx.x == 0) mnext[c] = outm[q];
      }
    }
  }
  __syncthreads();

  const float m0 = s_mean[512];
  const float4* mp4 = (const float4*)s_mean;                   // aligned: spatial at 0
  const float4 mkA0 = mp4[2*sl],      mkA1 = mp4[2*sl + 1];    // cols 8sl..+8
  const float4 mkB0 = mp4[64 + 2*sl], mkB1 = mp4[64 + 2*sl + 1];

  float accf[16] = {};
  double acc_t = 0.0, acc_cc = 0.0;
  const float* __restrict__ ttab = ws->t_tab;

  LDH(Pa, Pb, p0 + 2);
  LDH(Qa, Qb, p0 + 3);
  Ra = Aa; Rb = Ab; Sa = Ba; Sb = Bb;

  // t-value 1-step register pipeline
  float tAc = ttab[2 * p0 + half];
  float tBc = ttab[2 * (p0 + 1) + half];

  for (int kk = 0; kk < PPW; kk += 2) {
    if (kk + 4 < PPW) {
      LDH(Ra, Rb, p0 + kk + 4);
      LDH(Sa, Sb, p0 + kk + 5);
    }
    float tAn = 0.f, tBn = 0.f;
    if (kk + 2 < PPW) {
      tAn = ttab[2 * (p0 + kk + 2) + half];
      tBn = ttab[2 * (p0 + kk + 3) + half];
    }
    const float tA = tAc;
    const float tB = tBc;

    float2 f;
    f = cvt2(Aa.x); float dA  = f.x * mkA0.x;        dA  = fmaf(f.y, mkA0.y, dA);
    f = cvt2(Aa.y); dA  = fmaf(f.x, mkA0.z, dA);     dA  = fmaf(f.y, mkA0.w, dA);
    f = cvt2(Aa.z); dA  = fmaf(f.x, mkA1.x, dA);     dA  = fmaf(f.y, mkA1.y, dA);
    f = cvt2(Aa.w); dA  = fmaf(f.x, mkA1.z, dA);     dA  = fmaf(f.y, mkA1.w, dA);
    f = cvt2(Ab.x); float dA2 = f.x * mkB0.x;        dA2 = fmaf(f.y, mkB0.y, dA2);
    f = cvt2(Ab.y); dA2 = fmaf(f.x, mkB0.z, dA2);    dA2 = fmaf(f.y, mkB0.w, dA2);
    f = cvt2(Ab.z); dA2 = fmaf(f.x, mkB1.x, dA2);    dA2 = fmaf(f.y, mkB1.y, dA2);
    f = cvt2(Ab.w); dA2 = fmaf(f.x, mkB1.z, dA2);    dA2 = fmaf(f.y, mkB1.w, dA2);
    float dotA = dA + dA2;

    f = cvt2(Ba.x); float dB  = f.x * mkA0.x;        dB  = fmaf(f.y, mkA0.y, dB);
    f = cvt2(Ba.y); dB  = fmaf(f.x, mkA0.z, dB);     dB  = fmaf(f.y, mkA0.w, dB);
    f = cvt2(Ba.z); dB  = fmaf(f.x, mkA1.x, dB);     dB  = fmaf(f.y, mkA1.y, dB);
    f = cvt2(Ba.w); dB  = fmaf(f.x, mkA1.z, dB);     dB  = fmaf(f.y, mkA1.w, dB);
    f = cvt2(Bb.x); float dB2 = f.x * mkB0.x;        dB2 = fmaf(f.y, mkB0.y, dB2);
    f = cvt2(Bb.y); dB2 = fmaf(f.x, mkB0.z, dB2);    dB2 = fmaf(f.y, mkB0.w, dB2);
    f = cvt2(Bb.z); dB2 = fmaf(f.x, mkB1.x, dB2);    dB2 = fmaf(f.y, mkB1.y, dB2);
    f = cvt2(Bb.w); dB2 = fmaf(f.x, mkB1.z, dB2);    dB2 = fmaf(f.y, mkB1.w, dB2);
    float dotB = dB + dB2;

    #pragma unroll
    for (int m = 1; m < 32; m <<= 1) {
      dotA += __shfl_xor(dotA, m);
      dotB += __shfl_xor(dotB, m);
    }

    const float aA = fmaf(m0, tA, -dotA);
    const float aB = fmaf(m0, tB, -dotB);
    const float xA = fmaxf(aA, 1.0f + 1e-5f);
    const float xB = fmaxf(aB, 1.0f + 1e-5f);
    const float sA = sqrtf(fmaf(xA, xA, -1.0f));
    const float sB = sqrtf(fmaf(xB, xB, -1.0f));
    const float ddA = logf(xA + sA);
    const float ddB = logf(xB + sB);
    const float wA = ddA / sA;
    const float wB = ddB / sB;
    if (sl == 0) {
      acc_cc += fma((double)wA, (double)xA, (double)wB * (double)xB);
      acc_t  += fma((double)wA, (double)tA, (double)wB * (double)tB);
    }

    float2 a0, a1;
    a0 = cvt2(Aa.x); a1 = cvt2(Ba.x);
    accf[0]  = fmaf(wA, a0.x, fmaf(wB, a1.x, accf[0]));
    accf[1]  = fmaf(wA, a0.y, fmaf(wB, a1.y, accf[1]));
    a0 = cvt2(Aa.y); a1 = cvt2(Ba.y);
    accf[2]  = fmaf(wA, a0.x, fmaf(wB, a1.x, accf[2]));
    accf[3]  = fmaf(wA, a0.y, fmaf(wB, a1.y, accf[3]));
    a0 = cvt2(Aa.z); a1 = cvt2(Ba.z);
    accf[4]  = fmaf(wA, a0.x, fmaf(wB, a1.x, accf[4]));
    accf[5]  = fmaf(wA, a0.y, fmaf(wB, a1.y, accf[5]));
    a0 = cvt2(Aa.w); a1 = cvt2(Ba.w);
    accf[6]  = fmaf(wA, a0.x, fmaf(wB, a1.x, accf[6]));
    accf[7]  = fmaf(wA, a0.y, fmaf(wB, a1.y, accf[7]));
    a0 = cvt2(Ab.x); a1 = cvt2(Bb.x);
    accf[8]  = fmaf(wA, a0.x, fmaf(wB, a1.x, accf[8]));
    accf[9]  = fmaf(wA, a0.y, fmaf(wB, a1.y, accf[9]));
    a0 = cvt2(Ab.y); a1 = cvt2(Bb.y);
    accf[10] = fmaf(wA, a0.x, fmaf(wB, a1.x, accf[10]));
    accf[11] = fmaf(wA, a0.y, fmaf(wB, a1.y, accf[11]));
    a0 = cvt2(Ab.z); a1 = cvt2(Bb.z);
    accf[12] = fmaf(wA, a0.x, fmaf(wB, a1.x, accf[12]));
    accf[13] = fmaf(wA, a0.y, fmaf(wB, a1.y, accf[13]));
    a0 = cvt2(Ab.w); a1 = cvt2(Bb.w);
    accf[14] = fmaf(wA, a0.x, fmaf(wB, a1.x, accf[14]));
    accf[15] = fmaf(wA, a0.y, fmaf(wB, a1.y, accf[15]));

    Aa = Pa; Ab = Pb; Ba = Qa; Bb = Qb;
    Pa = Ra; Pb = Rb; Qa = Sa; Qb = Sb;
    tAc = tAn; tBc = tBn;
  }
#undef LDH

  #pragma unroll
  for (int i = 0; i < 16; ++i) accf[i] += __shfl_xor(accf[i], 32);
  acc_t  += __shfl_xor(acc_t, 32);
  acc_cc += __shfl_xor(acc_cc, 32);

  __shared__ double s_red[WPB][514];
  if (half == 0) {
    #pragma unroll
    for (int i = 0; i < 8; ++i) {
      s_red[wid][8*sl + i]       = (double)accf[i];
      s_red[wid][256 + 8*sl + i] = (double)accf[8 + i];
    }
  }
  if (l == 0) { s_red[wid][512] = acc_t; s_red[wid][513] = acc_cc; }
  __syncthreads();

  for (int c = threadIdx.x; c < 514; c += BLK) {
    double s = 0.0;
    #pragma unroll
    for (int w2 = 0; w2 < WPB; ++w2) s += s_red[w2][c];
    ws->part[c][blockIdx.x] = s;
  }
}

// ---------------- per-column reduce: one wave per column ----------------
__global__ __launch_bounds__(64)
void colreduce_kernel(Ws* __restrict__ ws)
{
  const int c = blockIdx.x;
  const int l = threadIdx.x;
  const double* col = ws->part[c];
  double s = 0.0;
  #pragma unroll
  for (int k = 0; k < GRID / 64; ++k) s += col[l + 64 * k];
  #pragma unroll
  for (int m = 1; m < 64; m <<= 1) s += __shfl_xor(s, m);
  if (l == 0) ws->colsum[c] = s;
}

// ---------------- final mean (one wave), after the last colreduce ----------------
__global__ __launch_bounds__(64)
void final_kernel(Ws* __restrict__ ws, const float* __restrict__ mprev,
                  float* __restrict__ mnext)
{
  float outm[9];
  compute_mean<false>(ws, mprev, threadIdx.x, outm);
  #pragma unroll
  for (int q = 0; q < 9; ++q) {
    int c = q * 64 + threadIdx.x;
    if (c < D1) mnext[c] = outm[q];
  }
}

__global__ void write_out_kernel(const float* __restrict__ mean, float* __restrict__ out)
{
  int i = threadIdx.x;
  if (i < SDIM) out[i] = mean[i];   // spatial components live at [0..511]
}

extern "C" void kernel_launch(void* const* d_in, const int* in_sizes, int n_in,
                              void* d_out, int out_size, void* d_ws, size_t ws_size,
                              hipStream_t stream)
{
  (void)in_sizes; (void)n_in; (void)out_size; (void)ws_size;
  const float* data = (const float*)d_in[0];
  Ws* ws = (Ws*)d_ws;

  const size_t hoff = (sizeof(Ws) + 255) & ~(size_t)255;
  __half* hdata = (__half*)((char*)d_ws + hoff);

  float* M0 = (float*)((char*)d_ws + offsetof(Ws, meanbuf));        // slot 0
  float* M1 = M0 + 516;                                             // slot 1

  init_kernel<<<dim3(GRID), dim3(BLK), 0, stream>>>(data, hdata, ws);
  colreduce_kernel<<<dim3(514), dim3(64), 0, stream>>>(ws);

  // iter #0: prologue computes mean_0 (INIT semantics) -> writes M0
  iter_kernel<true><<<dim3(GRID), dim3(BLK), 0, stream>>>(hdata, ws, M1, M0);
  colreduce_kernel<<<dim3(514), dim3(64), 0, stream>>>(ws);

  // iters #1..99: prologue computes mean_it from (colsum, mean_{it-1})
  for (int it = 1; it < NITER; ++it) {
    const float* mp = (((it + 1) & 1) == 0) ? M0 : M1;
    float*       mn = ((it & 1) == 0) ? M0 : M1;
    iter_kernel<false><<<dim3(GRID), dim3(BLK), 0, stream>>>(hdata, ws, mp, mn);
    colreduce_kernel<<<dim3(514), dim3(64), 0, stream>>>(ws);
  }

  // mean_100 from the last colreduce + mean_99 (it=99 wrote M1)
  final_kernel<<<dim3(1), dim3(64), 0, stream>>>(ws, M1, M0);
  write_out_kernel<<<dim3(1), dim3(512), 0, stream>>>(M0, (float*)d_out);
}